// Round 4
// baseline (343.743 us; speedup 1.0000x reference)
//
#include <hip/hip_runtime.h>
#include <hip/hip_bf16.h>

// Problem constants (fixed by reference). ALL float tensors are float32
// (reference is pure jnp.float32); indices int32. MFMA runs on bf16-converted
// fragments internally; accumulate + epilogue in fp32; output stored fp32.
#define NB     131072   // batch
#define NCH    16       // charts
#define NPAIR  256      // (src,tgt) pair buckets
#define LDH    136      // LDS row stride in bf16 elems (rows stay 16B-aligned)

// Workspace layout (ints): hist/cursor @0 (256) | off @256 (257) | sorted @528 (NB)
#define WS_HIST   0
#define WS_OFF    256
#define WS_SORTED 528
#define WS_BYTES  ((WS_SORTED + NB) * 4)   // 526,400

typedef short short8 __attribute__((ext_vector_type(8)));   // 8 x bf16 (4 VGPRs) MFMA frag
typedef float f32x4  __attribute__((ext_vector_type(4)));   // MFMA accumulator / fp32 vec

__device__ __forceinline__ short bfbits(float x) {
    union { __hip_bfloat16 h; short s; } u;
    u.h = __float2bfloat16(x);
    return u.s;
}

// Load 8 consecutive fp32 (32B, 16B-aligned) and convert to a bf16x8 MFMA frag.
__device__ __forceinline__ short8 cvt_frag(const float* __restrict__ p) {
    const f32x4 lo = *(const f32x4*)p;
    const f32x4 hi = *(const f32x4*)(p + 4);
    short8 r;
    r[0] = bfbits(lo[0]); r[1] = bfbits(lo[1]); r[2] = bfbits(lo[2]); r[3] = bfbits(lo[3]);
    r[4] = bfbits(hi[0]); r[5] = bfbits(hi[1]); r[6] = bfbits(hi[2]); r[7] = bfbits(hi[3]);
    return r;
}

// ---------------------------------------------------------------- k_init ----
__global__ void k_init(int* __restrict__ hist) {
    hist[threadIdx.x] = 0;
}

// ---------------------------------------------------------------- k_hist ----
__global__ __launch_bounds__(256) void k_hist(const int* __restrict__ si,
                                              const int* __restrict__ ti,
                                              int* __restrict__ hist) {
    __shared__ int sh[NPAIR];
    const int t = threadIdx.x;
    sh[t] = 0;
    __syncthreads();
    const int base = blockIdx.x * 2048 + t;
#pragma unroll
    for (int j = 0; j < 8; ++j) {
        const int i = base + j * 256;                       // coalesced
        const int k = (si[i] * NCH + ti[i]) & (NPAIR - 1);  // masked: never OOB
        atomicAdd(&sh[k], 1);
    }
    __syncthreads();
    if (sh[t]) atomicAdd(&hist[t], sh[t]);
}

// ---------------------------------------------------------------- k_scan ----
__global__ __launch_bounds__(256) void k_scan(int* __restrict__ hist,
                                              int* __restrict__ off) {
    __shared__ int s[NPAIR];
    const int t = threadIdx.x;
    const int v = hist[t];
    s[t] = v;
    __syncthreads();
#pragma unroll
    for (int d = 1; d < NPAIR; d <<= 1) {
        const int x = (t >= d) ? s[t - d] : 0;
        __syncthreads();
        s[t] += x;
        __syncthreads();
    }
    off[t + 1] = s[t];                 // inclusive -> off[1..256]
    if (t == 0) off[0] = 0;
    hist[t] = s[t] - v;                // exclusive prefix -> cursor start
}

// ------------------------------------------------------------- k_scatter ----
__global__ __launch_bounds__(256) void k_scatter(const int* __restrict__ si,
                                                 const int* __restrict__ ti,
                                                 int* __restrict__ cursor,
                                                 int* __restrict__ sorted) {
    __shared__ int sh[NPAIR];
    __shared__ int sbase[NPAIR];
    const int t = threadIdx.x;
    sh[t] = 0;
    __syncthreads();
    int key[8], rank[8];
    const int base = blockIdx.x * 2048 + t;
#pragma unroll
    for (int j = 0; j < 8; ++j) {
        const int i = base + j * 256;
        const int k = (si[i] * NCH + ti[i]) & (NPAIR - 1);
        key[j]  = k;
        rank[j] = atomicAdd(&sh[k], 1);
    }
    __syncthreads();
    sbase[t] = sh[t] ? atomicAdd(&cursor[t], sh[t]) : 0;
    __syncthreads();
#pragma unroll
    for (int j = 0; j < 8; ++j) {
        const int slot = sbase[key[j]] + rank[j];
        if (slot >= 0 && slot < NB)
            sorted[slot] = base + j * 256;
    }
}

// ---------------------------------------------------------------- k_gemm ----
// grid (8, 256): blockIdx.y = bucket, blockIdx.x strides over 128-row tiles.
// 256 threads = 4 waves; wave w owns rows [w*32, w*32+32) of the tile.
// GEMM1: h[m][r] = sum_d z[m][d]*W1[r][d] + c[r]   (A = gathered z rows)
// GEMM2: o[m][e] = sum_r h[m][r]*W2[e][r] + d[e]   (A = h from LDS, bf16)
__global__ __launch_bounds__(256, 2)
void k_gemm(const float* __restrict__ z,
            const float* __restrict__ encw,
            const float* __restrict__ decw,
            const float* __restrict__ cpar,
            const float* __restrict__ dpar,
            const int* __restrict__ off,
            const int* __restrict__ sorted,
            float* __restrict__ out) {
    __shared__ int sRow[128];
    __shared__ __align__(16) __hip_bfloat16 sH[128 * LDH];  // h tile (bf16)

    const int bucket = blockIdx.y;
    const int srcc = bucket >> 4;
    const int tgtc = bucket & (NCH - 1);
    const int beg = off[bucket];
    const int end = off[bucket + 1];

    const int tid  = threadIdx.x;
    const int lane = tid & 63;
    const int wv   = tid >> 6;
    const int lr   = lane & 15;                 // A: m-within-tile / B: n-within-tile
    const int lhi  = lane >> 4;                 // k-chunk selector (8 elems each)
    const int mb   = wv * 32;                   // this wave's row base in the tile

    const float* W1 = encw + srcc * 16384;      // [R=128][D=128] row-major fp32
    const float* W2 = decw + tgtc * 16384;      // [D=128][R=128] row-major fp32

    for (int tile = blockIdx.x; beg + tile * 128 < end; tile += (int)gridDim.x) {
        const int rbeg = beg + tile * 128;
        if (tid < 128) {
            const int g = rbeg + tid;
            int v = (g < end) ? sorted[g] : -1;
            sRow[tid] = ((unsigned)v < (unsigned)NB) ? v : -1;   // clamp: poison -> pad
        }
        __syncthreads();

        // -------- GEMM1: A rows gathered from global z (fp32 -> bf16) --------
        const int r0 = sRow[mb + lr];
        const int r1 = sRow[mb + 16 + lr];
        const float* pz0 = z + (long)(r0 < 0 ? 0 : r0) * 128 + lhi * 8;
        const float* pz1 = z + (long)(r1 < 0 ? 0 : r1) * 128 + lhi * 8;

        f32x4 acc[2][8];
#pragma unroll
        for (int mt = 0; mt < 2; ++mt)
#pragma unroll
            for (int nt = 0; nt < 8; ++nt) acc[mt][nt] = (f32x4)(0.0f);

#pragma unroll
        for (int k0 = 0; k0 < 128; k0 += 32) {
            const short8 a0 = cvt_frag(pz0 + k0);
            const short8 a1 = cvt_frag(pz1 + k0);
#pragma unroll
            for (int nt = 0; nt < 8; ++nt) {
                const short8 b = cvt_frag(W1 + (nt * 16 + lr) * 128 + k0 + lhi * 8);
                acc[0][nt] = __builtin_amdgcn_mfma_f32_16x16x32_bf16(a0, b, acc[0][nt], 0, 0, 0);
                acc[1][nt] = __builtin_amdgcn_mfma_f32_16x16x32_bf16(a1, b, acc[1][nt], 0, 0, 0);
            }
        }

        // h (+ c bias) -> LDS bf16 [m][r]; C layout: row=(lane>>4)*4+reg, col=lane&15
#pragma unroll
        for (int nt = 0; nt < 8; ++nt) {
            const float cb = cpar[srcc * 128 + nt * 16 + lr];
#pragma unroll
            for (int mt = 0; mt < 2; ++mt) {
                const int row = mb + mt * 16 + lhi * 4;
                const int col = nt * 16 + lr;
#pragma unroll
                for (int r = 0; r < 4; ++r)
                    sH[(row + r) * LDH + col] = __float2bfloat16(acc[mt][nt][r] + cb);
            }
        }
        __syncthreads();   // h crosses lanes via LDS — barrier required

        // -------- GEMM2: A = h from LDS (already bf16) --------
#pragma unroll
        for (int mt = 0; mt < 2; ++mt)
#pragma unroll
            for (int nt = 0; nt < 8; ++nt) acc[mt][nt] = (f32x4)(0.0f);

#pragma unroll
        for (int k0 = 0; k0 < 128; k0 += 32) {
            const short8 a0 = *(const short8*)(sH + (mb + lr) * LDH + k0 + lhi * 8);
            const short8 a1 = *(const short8*)(sH + (mb + 16 + lr) * LDH + k0 + lhi * 8);
#pragma unroll
            for (int nt = 0; nt < 8; ++nt) {
                const short8 b = cvt_frag(W2 + (nt * 16 + lr) * 128 + k0 + lhi * 8);
                acc[0][nt] = __builtin_amdgcn_mfma_f32_16x16x32_bf16(a0, b, acc[0][nt], 0, 0, 0);
                acc[1][nt] = __builtin_amdgcn_mfma_f32_16x16x32_bf16(a1, b, acc[1][nt], 0, 0, 0);
            }
        }

        // epilogue (+ d bias): store fp32 straight from accumulators.
        // For fixed (mt,r): lanes lr=0..15 write 16 consecutive floats (64B seg).
        {
            float db[8];
#pragma unroll
            for (int nt = 0; nt < 8; ++nt) db[nt] = dpar[tgtc * 128 + nt * 16 + lr];
#pragma unroll
            for (int mt = 0; mt < 2; ++mt)
#pragma unroll
                for (int r = 0; r < 4; ++r) {
                    const int grow = sRow[mb + mt * 16 + lhi * 4 + r];
                    if (grow >= 0) {
                        float* po = out + (long)grow * 128 + lr;
#pragma unroll
                        for (int nt = 0; nt < 8; ++nt)
                            po[nt * 16] = acc[mt][nt][r] + db[nt];
                    }
                }
        }
        __syncthreads();   // protect sRow/sH before next grid-stride tile
    }
}

// ------------------------------------------------------------- k_fallback ---
// Zero-workspace correct path: one wave per row, fp32 VALU dot products.
__global__ __launch_bounds__(256)
void k_fallback(const float* __restrict__ z,
                const int* __restrict__ si, const int* __restrict__ ti,
                const float* __restrict__ ew,
                const float* __restrict__ dw,
                const float* __restrict__ cp,
                const float* __restrict__ dp,
                float* __restrict__ out) {
    __shared__ float sh[4][128];
    const int lane = threadIdx.x & 63, wv = threadIdx.x >> 6;
    // NB/(1024*4) = 32 iterations, uniform for every wave -> barriers are safe.
    for (int row = blockIdx.x * 4 + wv; row < NB; row += (int)gridDim.x * 4) {
        const int sc = si[row] & (NCH - 1), tc = ti[row] & (NCH - 1);
        const float* zr = z + (long)row * 128;
        const float* W1 = ew + sc * 16384;
        float h0 = cp[sc * 128 + lane];
        float h1 = cp[sc * 128 + lane + 64];
        for (int d = 0; d < 128; ++d) {
            const float zv = zr[d];
            h0 += zv * W1[lane * 128 + d];
            h1 += zv * W1[(lane + 64) * 128 + d];
        }
        sh[wv][lane] = h0;
        sh[wv][lane + 64] = h1;
        __syncthreads();
        const float* W2 = dw + tc * 16384;
        float o0 = dp[tc * 128 + lane];
        float o1 = dp[tc * 128 + lane + 64];
        for (int r = 0; r < 128; ++r) {
            const float hv = sh[wv][r];
            o0 += hv * W2[lane * 128 + r];
            o1 += hv * W2[(lane + 64) * 128 + r];
        }
        out[(long)row * 128 + lane] = o0;
        out[(long)row * 128 + lane + 64] = o1;
        __syncthreads();
    }
}

// ----------------------------------------------------------------- launch ---
extern "C" void kernel_launch(void* const* d_in, const int* in_sizes, int n_in,
                              void* d_out, int out_size, void* d_ws, size_t ws_size,
                              hipStream_t stream) {
    // Reference dtypes: all float tensors float32, indices int32, output float32.
    const float* z  = (const float*)d_in[0];
    const int*   si = (const int*)d_in[1];
    const int*   ti = (const int*)d_in[2];
    const float* ew = (const float*)d_in[3];
    const float* dw = (const float*)d_in[4];
    const float* cp = (const float*)d_in[5];
    const float* dp = (const float*)d_in[6];
    float* out = (float*)d_out;

    if (ws_size >= (size_t)WS_BYTES) {
        int* hist   = (int*)d_ws + WS_HIST;    // 256, becomes cursor after scan
        int* off    = (int*)d_ws + WS_OFF;     // 257
        int* sorted = (int*)d_ws + WS_SORTED;  // NB

        k_init<<<1, NPAIR, 0, stream>>>(hist);
        k_hist<<<64, 256, 0, stream>>>(si, ti, hist);
        k_scan<<<1, NPAIR, 0, stream>>>(hist, off);
        k_scatter<<<64, 256, 0, stream>>>(si, ti, hist, sorted);
        k_gemm<<<dim3(8, NPAIR), 256, 0, stream>>>(z, ew, dw, cp, dp, off, sorted, out);
    } else {
        k_fallback<<<1024, 256, 0, stream>>>(z, si, ti, ew, dw, cp, dp, out);
    }
}

// Round 5
// 330.968 us; speedup vs baseline: 1.0386x; 1.0386x over previous
//
#include <hip/hip_runtime.h>
#include <hip/hip_bf16.h>

// Problem constants (fixed by reference). ALL float tensors are float32;
// indices int32. MFMA runs on bf16-converted fragments; accumulate + epilogue
// in fp32; output staged in LDS and stored fp32 fully coalesced.
#define NB     131072   // batch
#define NCH    16       // charts
#define NPAIR  256      // (src,tgt) pair buckets
#define LDH    136      // LDS h-row stride in bf16 elems (rows stay 16B-aligned)
#define LDO    132      // LDS out-row stride in fp32 elems (rows stay 16B-aligned)

// Workspace layout (ints): hist/cursor @0 (256) | off @256 (257) | sorted @528 (NB)
#define WS_HIST   0
#define WS_OFF    256
#define WS_SORTED 528
#define WS_BYTES  ((WS_SORTED + NB) * 4)   // 526,400

typedef short short8 __attribute__((ext_vector_type(8)));   // 8 x bf16 (4 VGPRs) MFMA frag
typedef float f32x4  __attribute__((ext_vector_type(4)));   // MFMA accumulator / fp32 vec

__device__ __forceinline__ short bfbits(float x) {
    union { __hip_bfloat16 h; short s; } u;
    u.h = __float2bfloat16(x);
    return u.s;
}

// Load 8 consecutive fp32 (32B, 16B-aligned) and convert to a bf16x8 MFMA frag.
__device__ __forceinline__ short8 cvt_frag(const float* __restrict__ p) {
    const f32x4 lo = *(const f32x4*)p;
    const f32x4 hi = *(const f32x4*)(p + 4);
    short8 r;
    r[0] = bfbits(lo[0]); r[1] = bfbits(lo[1]); r[2] = bfbits(lo[2]); r[3] = bfbits(lo[3]);
    r[4] = bfbits(hi[0]); r[5] = bfbits(hi[1]); r[6] = bfbits(hi[2]); r[7] = bfbits(hi[3]);
    return r;
}

// ---------------------------------------------------------------- k_init ----
__global__ void k_init(int* __restrict__ hist) {
    hist[threadIdx.x] = 0;
}

// ---------------------------------------------------------------- k_hist ----
__global__ __launch_bounds__(256) void k_hist(const int* __restrict__ si,
                                              const int* __restrict__ ti,
                                              int* __restrict__ hist) {
    __shared__ int sh[NPAIR];
    const int t = threadIdx.x;
    sh[t] = 0;
    __syncthreads();
    const int base = blockIdx.x * 2048 + t;
#pragma unroll
    for (int j = 0; j < 8; ++j) {
        const int i = base + j * 256;                       // coalesced
        const int k = (si[i] * NCH + ti[i]) & (NPAIR - 1);  // masked: never OOB
        atomicAdd(&sh[k], 1);
    }
    __syncthreads();
    if (sh[t]) atomicAdd(&hist[t], sh[t]);
}

// ---------------------------------------------------------------- k_scan ----
__global__ __launch_bounds__(256) void k_scan(int* __restrict__ hist,
                                              int* __restrict__ off) {
    __shared__ int s[NPAIR];
    const int t = threadIdx.x;
    const int v = hist[t];
    s[t] = v;
    __syncthreads();
#pragma unroll
    for (int d = 1; d < NPAIR; d <<= 1) {
        const int x = (t >= d) ? s[t - d] : 0;
        __syncthreads();
        s[t] += x;
        __syncthreads();
    }
    off[t + 1] = s[t];                 // inclusive -> off[1..256]
    if (t == 0) off[0] = 0;
    hist[t] = s[t] - v;                // exclusive prefix -> cursor start
}

// ------------------------------------------------------------- k_scatter ----
__global__ __launch_bounds__(256) void k_scatter(const int* __restrict__ si,
                                                 const int* __restrict__ ti,
                                                 int* __restrict__ cursor,
                                                 int* __restrict__ sorted) {
    __shared__ int sh[NPAIR];
    __shared__ int sbase[NPAIR];
    const int t = threadIdx.x;
    sh[t] = 0;
    __syncthreads();
    int key[8], rank[8];
    const int base = blockIdx.x * 2048 + t;
#pragma unroll
    for (int j = 0; j < 8; ++j) {
        const int i = base + j * 256;
        const int k = (si[i] * NCH + ti[i]) & (NPAIR - 1);
        key[j]  = k;
        rank[j] = atomicAdd(&sh[k], 1);
    }
    __syncthreads();
    sbase[t] = sh[t] ? atomicAdd(&cursor[t], sh[t]) : 0;
    __syncthreads();
#pragma unroll
    for (int j = 0; j < 8; ++j) {
        const int slot = sbase[key[j]] + rank[j];
        if (slot >= 0 && slot < NB)
            sorted[slot] = base + j * 256;
    }
}

// ---------------------------------------------------------------- k_gemm ----
// grid (8, 256): blockIdx.y = bucket, blockIdx.x strides over 128-row tiles.
// 256 threads = 4 waves; wave w owns rows [w*32, w*32+32) of the tile.
// GEMM1: h[m][r] = sum_d z[m][d]*W1[r][d] + c[r]   (A = gathered z rows)
// GEMM2: o[m][e] = sum_r h[m][r]*W2[e][r] + d[e]   (A = h from LDS, bf16)
// Output staged in LDS (fp32) and written as whole 512B rows, dwordx4/lane:
// the round-4 scalar epilogue caused partial-line RMW (WRITE 227MB vs 64MB).
__global__ __launch_bounds__(256, 2)
void k_gemm(const float* __restrict__ z,
            const float* __restrict__ encw,
            const float* __restrict__ decw,
            const float* __restrict__ cpar,
            const float* __restrict__ dpar,
            const int* __restrict__ off,
            const int* __restrict__ sorted,
            float* __restrict__ out) {
    __shared__ int sRow[128];
    __shared__ __align__(16) float sOut[128 * LDO];          // 67,584 B
    __hip_bfloat16* const sH = (__hip_bfloat16*)sOut;        // overlay: h tile (35 KB), dead
                                                             // before sOut is written

    const int bucket = blockIdx.y;
    const int srcc = bucket >> 4;
    const int tgtc = bucket & (NCH - 1);
    const int beg = off[bucket];
    const int end = off[bucket + 1];

    const int tid  = threadIdx.x;
    const int lane = tid & 63;
    const int wv   = tid >> 6;
    const int lr   = lane & 15;                 // A: m-within-tile / B: n-within-tile
    const int lhi  = lane >> 4;                 // k-chunk selector (8 elems each)
    const int mb   = wv * 32;                   // this wave's row base in the tile

    const float* W1 = encw + srcc * 16384;      // [R=128][D=128] row-major fp32
    const float* W2 = decw + tgtc * 16384;      // [D=128][R=128] row-major fp32

    for (int tile = blockIdx.x; beg + tile * 128 < end; tile += (int)gridDim.x) {
        const int rbeg = beg + tile * 128;
        if (tid < 128) {
            const int g = rbeg + tid;
            int v = (g < end) ? sorted[g] : -1;
            sRow[tid] = ((unsigned)v < (unsigned)NB) ? v : -1;   // clamp: poison -> pad
        }
        __syncthreads();

        // -------- GEMM1: A rows gathered from global z (fp32 -> bf16) --------
        const int r0 = sRow[mb + lr];
        const int r1 = sRow[mb + 16 + lr];
        const float* pz0 = z + (long)(r0 < 0 ? 0 : r0) * 128 + lhi * 8;
        const float* pz1 = z + (long)(r1 < 0 ? 0 : r1) * 128 + lhi * 8;

        f32x4 acc[2][8];
#pragma unroll
        for (int mt = 0; mt < 2; ++mt)
#pragma unroll
            for (int nt = 0; nt < 8; ++nt) acc[mt][nt] = (f32x4)(0.0f);

#pragma unroll
        for (int k0 = 0; k0 < 128; k0 += 32) {
            const short8 a0 = cvt_frag(pz0 + k0);
            const short8 a1 = cvt_frag(pz1 + k0);
#pragma unroll
            for (int nt = 0; nt < 8; ++nt) {
                const short8 b = cvt_frag(W1 + (nt * 16 + lr) * 128 + k0 + lhi * 8);
                acc[0][nt] = __builtin_amdgcn_mfma_f32_16x16x32_bf16(a0, b, acc[0][nt], 0, 0, 0);
                acc[1][nt] = __builtin_amdgcn_mfma_f32_16x16x32_bf16(a1, b, acc[1][nt], 0, 0, 0);
            }
        }

        // h (+ c bias) -> LDS bf16 [m][r]; C layout: row=(lane>>4)*4+reg, col=lane&15
#pragma unroll
        for (int nt = 0; nt < 8; ++nt) {
            const float cb = cpar[srcc * 128 + nt * 16 + lr];
#pragma unroll
            for (int mt = 0; mt < 2; ++mt) {
                const int row = mb + mt * 16 + lhi * 4;
                const int col = nt * 16 + lr;
#pragma unroll
                for (int r = 0; r < 4; ++r)
                    sH[(row + r) * LDH + col] = __float2bfloat16(acc[mt][nt][r] + cb);
            }
        }
        __syncthreads();   // h crosses lanes via LDS — fence/barrier required

        // -------- GEMM2: A = h from LDS (already bf16) --------
#pragma unroll
        for (int mt = 0; mt < 2; ++mt)
#pragma unroll
            for (int nt = 0; nt < 8; ++nt) acc[mt][nt] = (f32x4)(0.0f);

#pragma unroll
        for (int k0 = 0; k0 < 128; k0 += 32) {
            const short8 a0 = *(const short8*)(sH + (mb + lr) * LDH + k0 + lhi * 8);
            const short8 a1 = *(const short8*)(sH + (mb + 16 + lr) * LDH + k0 + lhi * 8);
#pragma unroll
            for (int nt = 0; nt < 8; ++nt) {
                const short8 b = cvt_frag(W2 + (nt * 16 + lr) * 128 + k0 + lhi * 8);
                acc[0][nt] = __builtin_amdgcn_mfma_f32_16x16x32_bf16(a0, b, acc[0][nt], 0, 0, 0);
                acc[1][nt] = __builtin_amdgcn_mfma_f32_16x16x32_bf16(a1, b, acc[1][nt], 0, 0, 0);
            }
        }
        __syncthreads();   // all sH reads done before overwriting the overlay

        // epilogue (+ d bias) -> sOut fp32 [m][e], stride LDO
        // banks: same-(lr,nt) lanes in lhi-groups {0,2} and {1,3} alias 2-way (free)
#pragma unroll
        for (int nt = 0; nt < 8; ++nt) {
            const float db = dpar[tgtc * 128 + nt * 16 + lr];
#pragma unroll
            for (int mt = 0; mt < 2; ++mt) {
                const int row = mb + mt * 16 + lhi * 4;
                const int col = nt * 16 + lr;
#pragma unroll
                for (int r = 0; r < 4; ++r)
                    sOut[(row + r) * LDO + col] = acc[mt][nt][r] + db;
            }
        }
        __syncthreads();

        // coalesced store: 32 lanes x 16B = one whole 512B row; 2 rows/wave/instr
        {
            const int rr0 = tid >> 5;          // 0..7
            const int c4  = (tid & 31) * 4;    // float offset, 16B granules
#pragma unroll
            for (int it = 0; it < 16; ++it) {
                const int rr = rr0 + it * 8;
                const int grow = sRow[rr];
                if (grow >= 0)
                    *(f32x4*)(out + (long)grow * 128 + c4) =
                        *(const f32x4*)(sOut + rr * LDO + c4);
            }
        }
        __syncthreads();   // protect sRow/sOut before next grid-stride tile
    }
}

// ------------------------------------------------------------- k_fallback ---
// Zero-workspace correct path: one wave per row, fp32 VALU dot products.
__global__ __launch_bounds__(256)
void k_fallback(const float* __restrict__ z,
                const int* __restrict__ si, const int* __restrict__ ti,
                const float* __restrict__ ew,
                const float* __restrict__ dw,
                const float* __restrict__ cp,
                const float* __restrict__ dp,
                float* __restrict__ out) {
    __shared__ float sh[4][128];
    const int lane = threadIdx.x & 63, wv = threadIdx.x >> 6;
    for (int row = blockIdx.x * 4 + wv; row < NB; row += (int)gridDim.x * 4) {
        const int sc = si[row] & (NCH - 1), tc = ti[row] & (NCH - 1);
        const float* zr = z + (long)row * 128;
        const float* W1 = ew + sc * 16384;
        float h0 = cp[sc * 128 + lane];
        float h1 = cp[sc * 128 + lane + 64];
        for (int d = 0; d < 128; ++d) {
            const float zv = zr[d];
            h0 += zv * W1[lane * 128 + d];
            h1 += zv * W1[(lane + 64) * 128 + d];
        }
        sh[wv][lane] = h0;
        sh[wv][lane + 64] = h1;
        __syncthreads();
        const float* W2 = dw + tc * 16384;
        float o0 = dp[tc * 128 + lane];
        float o1 = dp[tc * 128 + lane + 64];
        for (int r = 0; r < 128; ++r) {
            const float hv = sh[wv][r];
            o0 += hv * W2[lane * 128 + r];
            o1 += hv * W2[(lane + 64) * 128 + r];
        }
        out[(long)row * 128 + lane] = o0;
        out[(long)row * 128 + lane + 64] = o1;
        __syncthreads();
    }
}

// ----------------------------------------------------------------- launch ---
extern "C" void kernel_launch(void* const* d_in, const int* in_sizes, int n_in,
                              void* d_out, int out_size, void* d_ws, size_t ws_size,
                              hipStream_t stream) {
    // Reference dtypes: all float tensors float32, indices int32, output float32.
    const float* z  = (const float*)d_in[0];
    const int*   si = (const int*)d_in[1];
    const int*   ti = (const int*)d_in[2];
    const float* ew = (const float*)d_in[3];
    const float* dw = (const float*)d_in[4];
    const float* cp = (const float*)d_in[5];
    const float* dp = (const float*)d_in[6];
    float* out = (float*)d_out;

    if (ws_size >= (size_t)WS_BYTES) {
        int* hist   = (int*)d_ws + WS_HIST;    // 256, becomes cursor after scan
        int* off    = (int*)d_ws + WS_OFF;     // 257
        int* sorted = (int*)d_ws + WS_SORTED;  // NB

        k_init<<<1, NPAIR, 0, stream>>>(hist);
        k_hist<<<64, 256, 0, stream>>>(si, ti, hist);
        k_scan<<<1, NPAIR, 0, stream>>>(hist, off);
        k_scatter<<<64, 256, 0, stream>>>(si, ti, hist, sorted);
        k_gemm<<<dim3(8, NPAIR), 256, 0, stream>>>(z, ew, dw, cp, dp, off, sorted, out);
    } else {
        k_fallback<<<1024, 256, 0, stream>>>(z, si, ti, ew, dw, cp, dp, out);
    }
}

// Round 6
// 162.737 us; speedup vs baseline: 2.1123x; 2.0338x over previous
//
#include <hip/hip_runtime.h>
#include <hip/hip_bf16.h>

// Problem constants (fixed by reference). ALL float tensors are float32;
// indices int32. MFMA runs on bf16-converted fragments; accumulate + epilogue
// in fp32; output staged in LDS and stored fp32 fully coalesced.
#define NB     131072   // batch
#define NCH    16       // charts
#define NPAIR  256      // (src,tgt) pair buckets
#define LDW    136      // LDS weight-row stride in bf16 elems (16B-aligned rows)
#define LDH    136      // LDS h-row stride in bf16 elems
#define LDO    132      // LDS out-row stride in fp32 elems

// Workspace layout (ints): hist/cursor @0 (256) | off @256 (257) | sorted @528 (NB)
#define WS_HIST   0
#define WS_OFF    256
#define WS_SORTED 528
#define WS_BYTES  ((WS_SORTED + NB) * 4)   // 526,400

typedef short short8 __attribute__((ext_vector_type(8)));   // 8 x bf16 (4 VGPRs) MFMA frag
typedef float f32x4  __attribute__((ext_vector_type(4)));   // MFMA accumulator / fp32 vec

__device__ __forceinline__ short bfbits(float x) {
    union { __hip_bfloat16 h; short s; } u;
    u.h = __float2bfloat16(x);
    return u.s;
}

// Load 8 consecutive fp32 (32B, 16B-aligned) and convert to a bf16x8 MFMA frag.
__device__ __forceinline__ short8 cvt_frag(const float* __restrict__ p) {
    const f32x4 lo = *(const f32x4*)p;
    const f32x4 hi = *(const f32x4*)(p + 4);
    short8 r;
    r[0] = bfbits(lo[0]); r[1] = bfbits(lo[1]); r[2] = bfbits(lo[2]); r[3] = bfbits(lo[3]);
    r[4] = bfbits(hi[0]); r[5] = bfbits(hi[1]); r[6] = bfbits(hi[2]); r[7] = bfbits(hi[3]);
    return r;
}

// ---------------------------------------------------------------- k_init ----
__global__ void k_init(int* __restrict__ hist) {
    hist[threadIdx.x] = 0;
}

// ---------------------------------------------------------------- k_hist ----
__global__ __launch_bounds__(256) void k_hist(const int* __restrict__ si,
                                              const int* __restrict__ ti,
                                              int* __restrict__ hist) {
    __shared__ int sh[NPAIR];
    const int t = threadIdx.x;
    sh[t] = 0;
    __syncthreads();
    const int base = blockIdx.x * 2048 + t;
#pragma unroll
    for (int j = 0; j < 8; ++j) {
        const int i = base + j * 256;                       // coalesced
        const int k = (si[i] * NCH + ti[i]) & (NPAIR - 1);  // masked: never OOB
        atomicAdd(&sh[k], 1);
    }
    __syncthreads();
    if (sh[t]) atomicAdd(&hist[t], sh[t]);
}

// ---------------------------------------------------------------- k_scan ----
__global__ __launch_bounds__(256) void k_scan(int* __restrict__ hist,
                                              int* __restrict__ off) {
    __shared__ int s[NPAIR];
    const int t = threadIdx.x;
    const int v = hist[t];
    s[t] = v;
    __syncthreads();
#pragma unroll
    for (int d = 1; d < NPAIR; d <<= 1) {
        const int x = (t >= d) ? s[t - d] : 0;
        __syncthreads();
        s[t] += x;
        __syncthreads();
    }
    off[t + 1] = s[t];                 // inclusive -> off[1..256]
    if (t == 0) off[0] = 0;
    hist[t] = s[t] - v;                // exclusive prefix -> cursor start
}

// ------------------------------------------------------------- k_scatter ----
__global__ __launch_bounds__(256) void k_scatter(const int* __restrict__ si,
                                                 const int* __restrict__ ti,
                                                 int* __restrict__ cursor,
                                                 int* __restrict__ sorted) {
    __shared__ int sh[NPAIR];
    __shared__ int sbase[NPAIR];
    const int t = threadIdx.x;
    sh[t] = 0;
    __syncthreads();
    int key[8], rank[8];
    const int base = blockIdx.x * 2048 + t;
#pragma unroll
    for (int j = 0; j < 8; ++j) {
        const int i = base + j * 256;
        const int k = (si[i] * NCH + ti[i]) & (NPAIR - 1);
        key[j]  = k;
        rank[j] = atomicAdd(&sh[k], 1);
    }
    __syncthreads();
    sbase[t] = sh[t] ? atomicAdd(&cursor[t], sh[t]) : 0;
    __syncthreads();
#pragma unroll
    for (int j = 0; j < 8; ++j) {
        const int slot = sbase[key[j]] + rank[j];
        if (slot >= 0 && slot < NB)
            sorted[slot] = base + j * 256;
    }
}

// ---------------------------------------------------------------- k_gemm ----
// ONE BLOCK PER BUCKET (grid 256 = 1 block/CU). Weights are staged ONCE into
// LDS as bf16 (round-5 re-read W1/W2 from global every tile -> serialized
// latency chain, 227us with all pipes <3%). Per tile the only global loads
// are 8 independent z-gather reads per wave; B operands come from regs/LDS.
// 256 threads = 4 waves; wave w owns rows [w*32, w*32+32) of the 128-row tile.
__global__ __launch_bounds__(256, 1)
void k_gemm(const float* __restrict__ z,
            const float* __restrict__ encw,
            const float* __restrict__ decw,
            const float* __restrict__ cpar,
            const float* __restrict__ dpar,
            const int* __restrict__ off,
            const int* __restrict__ sorted,
            float* __restrict__ out) {
    __shared__ int sRow[128];
    __shared__ __align__(16) __hip_bfloat16 sW1[128 * LDW];  // 34,816 B
    __shared__ __align__(16) __hip_bfloat16 sW2[128 * LDW];  // 34,816 B
    __shared__ __align__(16) float sOut[128 * LDO];          // 67,584 B
    __hip_bfloat16* const sH = (__hip_bfloat16*)sOut;        // overlay: h tile (35 KB)

    const int bucket = blockIdx.x;
    const int srcc = bucket >> 4;
    const int tgtc = bucket & (NCH - 1);
    const int beg = off[bucket];
    const int end = off[bucket + 1];

    const int tid  = threadIdx.x;
    const int lane = tid & 63;
    const int wv   = tid >> 6;
    const int lr   = lane & 15;                 // A: m-within-tile / B: n-within-tile
    const int lhi  = lane >> 4;                 // k-chunk selector (8 elems each)
    const int mb   = wv * 32;                   // this wave's row base in the tile

    // ---- stage W1/W2 (fp32 global, coalesced) -> bf16 LDS, once per block ----
    {
        const float* W1 = encw + srcc * 16384;  // [R=128][D=128] row-major fp32
        const float* W2 = decw + tgtc * 16384;  // [D=128][R=128] row-major fp32
#pragma unroll
        for (int it = 0; it < 8; ++it) {
            const int f = (it * 256 + tid) * 8;          // flat float index, 8 at a time
            const int row = f >> 7, col = f & 127;
            *(short8*)(sW1 + row * LDW + col) = cvt_frag(W1 + f);
            *(short8*)(sW2 + row * LDW + col) = cvt_frag(W2 + f);
        }
    }
    __syncthreads();

    // hoist GEMM1 B-fragments into registers (loop-invariant across tiles)
    short8 b1[8][4];
#pragma unroll
    for (int nt = 0; nt < 8; ++nt)
#pragma unroll
        for (int k = 0; k < 4; ++k)
            b1[nt][k] = *(const short8*)(sW1 + (nt * 16 + lr) * LDW + k * 32 + lhi * 8);

    float cb[8], db[8];
#pragma unroll
    for (int nt = 0; nt < 8; ++nt) {
        cb[nt] = cpar[srcc * 128 + nt * 16 + lr];
        db[nt] = dpar[tgtc * 128 + nt * 16 + lr];
    }

    const int ntile = (end - beg + 127) >> 7;
    for (int tile = 0; tile < ntile; ++tile) {
        const int rbeg = beg + tile * 128;
        __syncthreads();   // protect sRow/sOut from previous iteration's readers
        if (tid < 128) {
            const int g = rbeg + tid;
            int v = (g < end) ? sorted[g] : -1;
            sRow[tid] = ((unsigned)v < (unsigned)NB) ? v : -1;   // clamp: poison -> pad
        }
        __syncthreads();

        // -------- GEMM1: A rows gathered from global z (fp32 -> bf16) --------
        const int r0 = sRow[mb + lr];
        const int r1 = sRow[mb + 16 + lr];
        const float* pz0 = z + (long)(r0 < 0 ? 0 : r0) * 128 + lhi * 8;
        const float* pz1 = z + (long)(r1 < 0 ? 0 : r1) * 128 + lhi * 8;

        f32x4 acc[2][8];
#pragma unroll
        for (int mt = 0; mt < 2; ++mt)
#pragma unroll
            for (int nt = 0; nt < 8; ++nt) acc[mt][nt] = (f32x4)(0.0f);

#pragma unroll
        for (int k = 0; k < 4; ++k) {
            const short8 a0 = cvt_frag(pz0 + k * 32);
            const short8 a1 = cvt_frag(pz1 + k * 32);
#pragma unroll
            for (int nt = 0; nt < 8; ++nt) {
                acc[0][nt] = __builtin_amdgcn_mfma_f32_16x16x32_bf16(a0, b1[nt][k], acc[0][nt], 0, 0, 0);
                acc[1][nt] = __builtin_amdgcn_mfma_f32_16x16x32_bf16(a1, b1[nt][k], acc[1][nt], 0, 0, 0);
            }
        }

        // h (+ c bias) -> LDS bf16 [m][r]; C layout: row=(lane>>4)*4+reg, col=lane&15
#pragma unroll
        for (int nt = 0; nt < 8; ++nt)
#pragma unroll
            for (int mt = 0; mt < 2; ++mt) {
                const int row = mb + mt * 16 + lhi * 4;
                const int col = nt * 16 + lr;
#pragma unroll
                for (int r = 0; r < 4; ++r)
                    sH[(row + r) * LDH + col] = __float2bfloat16(acc[mt][nt][r] + cb[nt]);
            }
        __syncthreads();   // h crosses lanes via LDS — barrier required

        // -------- GEMM2: A = h from LDS (bf16), B = sW2 from LDS --------
#pragma unroll
        for (int mt = 0; mt < 2; ++mt)
#pragma unroll
            for (int nt = 0; nt < 8; ++nt) acc[mt][nt] = (f32x4)(0.0f);

#pragma unroll
        for (int k = 0; k < 4; ++k) {
            const short8 a0 = *(const short8*)(sH + (mb + lr) * LDH + k * 32 + lhi * 8);
            const short8 a1 = *(const short8*)(sH + (mb + 16 + lr) * LDH + k * 32 + lhi * 8);
#pragma unroll
            for (int nt = 0; nt < 8; ++nt) {
                const short8 b = *(const short8*)(sW2 + (nt * 16 + lr) * LDW + k * 32 + lhi * 8);
                acc[0][nt] = __builtin_amdgcn_mfma_f32_16x16x32_bf16(a0, b, acc[0][nt], 0, 0, 0);
                acc[1][nt] = __builtin_amdgcn_mfma_f32_16x16x32_bf16(a1, b, acc[1][nt], 0, 0, 0);
            }
        }
        __syncthreads();   // all sH reads done before overwriting the overlay

        // epilogue (+ d bias) -> sOut fp32 [m][e]
#pragma unroll
        for (int nt = 0; nt < 8; ++nt)
#pragma unroll
            for (int mt = 0; mt < 2; ++mt) {
                const int row = mb + mt * 16 + lhi * 4;
                const int col = nt * 16 + lr;
#pragma unroll
                for (int r = 0; r < 4; ++r)
                    sOut[(row + r) * LDO + col] = acc[mt][nt][r] + db[nt];
            }
        __syncthreads();

        // coalesced store: 32 lanes x 16B = one whole 512B row
        {
            const int rr0 = tid >> 5;          // 0..7
            const int c4  = (tid & 31) * 4;    // float offset, 16B granules
#pragma unroll
            for (int it = 0; it < 16; ++it) {
                const int rr = rr0 + it * 8;
                const int grow = sRow[rr];
                if (grow >= 0)
                    *(f32x4*)(out + (long)grow * 128 + c4) =
                        *(const f32x4*)(sOut + rr * LDO + c4);
            }
        }
    }
}

// ------------------------------------------------------------- k_fallback ---
// Zero-workspace correct path: one wave per row, fp32 VALU dot products.
__global__ __launch_bounds__(256)
void k_fallback(const float* __restrict__ z,
                const int* __restrict__ si, const int* __restrict__ ti,
                const float* __restrict__ ew,
                const float* __restrict__ dw,
                const float* __restrict__ cp,
                const float* __restrict__ dp,
                float* __restrict__ out) {
    __shared__ float sh[4][128];
    const int lane = threadIdx.x & 63, wv = threadIdx.x >> 6;
    for (int row = blockIdx.x * 4 + wv; row < NB; row += (int)gridDim.x * 4) {
        const int sc = si[row] & (NCH - 1), tc = ti[row] & (NCH - 1);
        const float* zr = z + (long)row * 128;
        const float* W1 = ew + sc * 16384;
        float h0 = cp[sc * 128 + lane];
        float h1 = cp[sc * 128 + lane + 64];
        for (int d = 0; d < 128; ++d) {
            const float zv = zr[d];
            h0 += zv * W1[lane * 128 + d];
            h1 += zv * W1[(lane + 64) * 128 + d];
        }
        sh[wv][lane] = h0;
        sh[wv][lane + 64] = h1;
        __syncthreads();
        const float* W2 = dw + tc * 16384;
        float o0 = dp[tc * 128 + lane];
        float o1 = dp[tc * 128 + lane + 64];
        for (int r = 0; r < 128; ++r) {
            const float hv = sh[wv][r];
            o0 += hv * W2[lane * 128 + r];
            o1 += hv * W2[(lane + 64) * 128 + r];
        }
        out[(long)row * 128 + lane] = o0;
        out[(long)row * 128 + lane + 64] = o1;
        __syncthreads();
    }
}

// ----------------------------------------------------------------- launch ---
extern "C" void kernel_launch(void* const* d_in, const int* in_sizes, int n_in,
                              void* d_out, int out_size, void* d_ws, size_t ws_size,
                              hipStream_t stream) {
    // Reference dtypes: all float tensors float32, indices int32, output float32.
    const float* z  = (const float*)d_in[0];
    const int*   si = (const int*)d_in[1];
    const int*   ti = (const int*)d_in[2];
    const float* ew = (const float*)d_in[3];
    const float* dw = (const float*)d_in[4];
    const float* cp = (const float*)d_in[5];
    const float* dp = (const float*)d_in[6];
    float* out = (float*)d_out;

    if (ws_size >= (size_t)WS_BYTES) {
        int* hist   = (int*)d_ws + WS_HIST;    // 256, becomes cursor after scan
        int* off    = (int*)d_ws + WS_OFF;     // 257
        int* sorted = (int*)d_ws + WS_SORTED;  // NB

        k_init<<<1, NPAIR, 0, stream>>>(hist);
        k_hist<<<64, 256, 0, stream>>>(si, ti, hist);
        k_scan<<<1, NPAIR, 0, stream>>>(hist, off);
        k_scatter<<<64, 256, 0, stream>>>(si, ti, hist, sorted);
        k_gemm<<<NPAIR, 256, 0, stream>>>(z, ew, dw, cp, dp, off, sorted, out);
    } else {
        k_fallback<<<1024, 256, 0, stream>>>(z, si, ti, ew, dw, cp, dp, out);
    }
}